// Round 8
// baseline (388.028 us; speedup 1.0000x reference)
//
#include <hip/hip_runtime.h>

// NSA attention.
// K0: init ck/cv with bias. K1: K-split compress (fp32, atomics).
// K2: cmp attention + topk (fp32 selection), writes g2-gated cmp_o into out.
// K3: branch-split MFMA flash attention: 768 blocks (192 tiles x 2 kv x 2 branch),
//     head-paired waves (rows 0-7 = head w, 8-15 = head w+4), P aliased over Vrow,
//     register prefetch, atomicAdd combine into out.

#define S_LEN 1536
#define HQ    16
#define HKV   2
#define DH    128
#define TC    95
#define WIN   512
#define TQ    8
#define SCALE 0.08838834764831845f   // 1/sqrt(128)

typedef _Float16 f16;
typedef f16   f16x4 __attribute__((ext_vector_type(4)));
typedef f16   f16x8 __attribute__((ext_vector_type(8)));
typedef float f32x4 __attribute__((ext_vector_type(4)));

__device__ inline f16x8 cvt8(float4 A, float4 B) {
    f16x8 h;
    h[0]=(f16)A.x; h[1]=(f16)A.y; h[2]=(f16)A.z; h[3]=(f16)A.w;
    h[4]=(f16)B.x; h[5]=(f16)B.y; h[6]=(f16)B.z; h[7]=(f16)B.w;
    return h;
}
__device__ inline f16x8 cvt8s(float4 A, float4 B, float s) {
    f16x8 h;
    h[0]=(f16)(A.x*s); h[1]=(f16)(A.y*s); h[2]=(f16)(A.z*s); h[3]=(f16)(A.w*s);
    h[4]=(f16)(B.x*s); h[5]=(f16)(B.y*s); h[6]=(f16)(B.z*s); h[7]=(f16)(B.w*s);
    return h;
}

// ---------------------------------------------------------------- kernel 0
__global__ __launch_bounds__(256) void compress_init_kernel(
    const float* __restrict__ bk, const float* __restrict__ bv,
    float* __restrict__ ck, float* __restrict__ cv)
{
    int i = blockIdx.x * 256 + threadIdx.x;       // 190 blocks * 256 = 48640
    int which = i >= TC*HKV*DH;
    int j = i - which*(TC*HKV*DH);
    int d = j & 127;
    (which ? cv : ck)[j] = (which ? bv : bk)[d];
}

// ---------------------------------------------------------------- kernel 1
__global__ __launch_bounds__(256) void compress_partial_kernel(
    const float* __restrict__ kin, const float* __restrict__ vin,
    const float* __restrict__ Wk,  const float* __restrict__ Wv,
    const float* __restrict__ pek, const float* __restrict__ pev,
    float* __restrict__ ck, float* __restrict__ cv)
{
    const int t0    = blockIdx.x * 5;
    const int kv    = blockIdx.y >> 1;
    const int which = blockIdx.y & 1;
    const int kc    = blockIdx.z;
    const float* __restrict__ x  = which ? vin : kin;
    const float* __restrict__ W  = which ? Wv  : Wk;
    const float* __restrict__ pe = which ? pev : pek;
    float* __restrict__ outp     = which ? cv  : ck;
    const int tid = threadIdx.x;
    const int hh  = tid >> 7;
    const int d   = tid & 127;

    __shared__ float xs[2][5][128];
    __shared__ float racc[5][128];
    float acc[5] = {0.f, 0.f, 0.f, 0.f, 0.f};

    #pragma unroll
    for (int il = 0; il < 2; ++il) {
        const int l = kc*4 + hh*2 + il;
        float p = pe[l*DH + d];
        #pragma unroll
        for (int tt = 0; tt < 5; ++tt) {
            int row = (t0 + tt)*16 + l;
            xs[hh][tt][d] = x[(row*HKV + kv)*DH + d] + p;
        }
        __syncthreads();
        const float* wcol = W + l*DH*DH + d;
        #pragma unroll 8
        for (int dd = 0; dd < 128; ++dd) {
            float wv = wcol[dd*DH];
            #pragma unroll
            for (int tt = 0; tt < 5; ++tt) acc[tt] += xs[hh][tt][dd] * wv;
        }
        __syncthreads();
    }
    if (hh == 1) {
        #pragma unroll
        for (int tt = 0; tt < 5; ++tt) racc[tt][d] = acc[tt];
    }
    __syncthreads();
    if (hh == 0) {
        #pragma unroll
        for (int tt = 0; tt < 5; ++tt)
            atomicAdd(&outp[((t0 + tt)*HKV + kv)*DH + d], acc[tt] + racc[tt][d]);
    }
}

// ---------------------------------------------------------------- kernel 2
// 4 queries/block; fp32 selection path; stores g2-gated cmp_o into out.
__global__ __launch_bounds__(256) void cmp_attn_kernel(
    const float* __restrict__ q, const float* __restrict__ ck,
    const float* __restrict__ cv, const float* __restrict__ Wg,
    const float* __restrict__ bg, float* __restrict__ outp,
    unsigned int* __restrict__ blk_mask)
{
    const int s0  = blockIdx.x * 4;
    const int kv  = blockIdx.y;
    const int tid = threadIdx.x;

    __shared__ __align__(16) float qs4[4][8*132];
    __shared__ __align__(16) f16  cvs[TC*132];
    __shared__ float lt[8][96];
    __shared__ float score[96];
    __shared__ float pooled[24];

    for (int i = tid; i < 4*8*128; i += 256) {
        int ss = i >> 10, rem = i & 1023;
        int g = rem >> 7, d = rem & 127;
        qs4[ss][g*132 + d] = q[(size_t)((s0+ss)*HQ + kv*8 + g)*DH + d];
    }
    for (int i = tid; i < TC*32; i += 256) {
        int t = i >> 5, c = i & 31;
        float4 a = *(const float4*)(cv + (size_t)(t*HKV + kv)*DH + c*4);
        f16x4 h; h[0]=(f16)a.x; h[1]=(f16)a.y; h[2]=(f16)a.z; h[3]=(f16)a.w;
        *(f16x4*)&cvs[t*132 + c*4] = h;
    }
    __syncthreads();

    const int sub  = tid & 7;
    const int g    = tid >> 5, lane = tid & 31;
    const float bg2 = bg[2];

    for (int ss = 0; ss < 4; ++ss) {
        const int s  = s0 + ss;
        const int nv = (s >= 31) ? (((s - 31) >> 4) + 1) : 0;

        for (int task = tid >> 3; task < 8*TC; task += 32) {
            int gg = task / TC, t = task - gg*TC;
            const float4* ckr = (const float4*)(ck + (size_t)(t*HKV + kv)*DH) + sub*4;
            const float*  qp  = qs4[ss] + gg*132 + sub*16;
            float acc = 0.f;
            #pragma unroll
            for (int j = 0; j < 4; ++j) {
                float4 b = ckr[j];
                const float* a = qp + j*4;
                acc += a[0]*b.x + a[1]*b.y + a[2]*b.z + a[3]*b.w;
            }
            #pragma unroll
            for (int off = 4; off; off >>= 1) acc += __shfl_xor(acc, off, 8);
            if (sub == 0) lt[gg][t] = acc * SCALE;
        }
        __syncthreads();

        float m = -3.4e38f;
        for (int t = lane; t < nv; t += 32) m = fmaxf(m, lt[g][t]);
        #pragma unroll
        for (int off = 16; off; off >>= 1) m = fmaxf(m, __shfl_xor(m, off, 32));
        float ssum = 0.f;
        for (int t = lane; t < TC; t += 32) {
            float e = (t < nv) ? __expf(lt[g][t] - m) : 0.f;
            lt[g][t] = e;
            ssum += e;
        }
        #pragma unroll
        for (int off = 16; off; off >>= 1) ssum += __shfl_xor(ssum, off, 32);
        const float inv = 1.f / fmaxf(ssum, 1e-9f);
        for (int t = lane; t < TC; t += 32) lt[g][t] *= inv;

        {
            float4 acc = make_float4(0.f, 0.f, 0.f, 0.f);
            #pragma unroll 5
            for (int t = 0; t < TC; ++t) {
                float p = lt[g][t];
                f16x4 h = *(const f16x4*)&cvs[t*132 + lane*4];
                acc.x += p*(float)h[0]; acc.y += p*(float)h[1];
                acc.z += p*(float)h[2]; acc.w += p*(float)h[3];
            }
            // g2 gate = sigmoid(q . Wg[:,2] + bg[2]) for (s, head g)
            float gp = 0.f;
            const float* qp2 = qs4[ss] + g*132 + lane*4;
            #pragma unroll
            for (int j = 0; j < 4; ++j) gp += qp2[j] * Wg[(lane*4+j)*3 + 2];
            #pragma unroll
            for (int off = 16; off; off >>= 1) gp += __shfl_xor(gp, off, 32);
            float g2 = 1.f/(1.f + __expf(-(gp + bg2)));
            float4 o;
            o.x = g2*acc.x; o.y = g2*acc.y; o.z = g2*acc.z; o.w = g2*acc.w;
            *(float4*)(outp + (size_t)(s*HQ + kv*8 + g)*DH + lane*4) = o;
        }
        __syncthreads();

        if (tid < TC) {
            float sc = 0.f;
            #pragma unroll
            for (int gg = 0; gg < 8; ++gg) sc += lt[gg][tid];
            score[tid] = sc;
        }
        __syncthreads();
        if (tid < 24) {
            float acc = 0.f, cnt = 0.f;
            #pragma unroll
            for (int j = 0; j < 5; ++j) {
                int w = tid*4 + j;
                if (w < TC) { acc += score[w]; cnt += 1.f; }
            }
            pooled[tid] = acc / cnt;
        }
        __syncthreads();
        bool sel = false;
        if (tid < 24) {
            float pvv = pooled[tid];
            int rank = 0;
            #pragma unroll
            for (int j = 0; j < 24; ++j) {
                float pj = pooled[j];
                rank += ((pj > pvv) || (pj == pvv && j < tid)) ? 1 : 0;
            }
            sel = rank < 16;
        }
        unsigned long long b = __ballot(sel);
        if (tid == 0) blk_mask[kv*S_LEN + s] = (unsigned int)(b & 0xFFFFFFull);
        __syncthreads();
    }
}

// ---------------------------------------------------------------- kernel 3
// Branch-split flash: grid (192, kv, branch). 256 thr = 4 waves; wave w packs
// head w in MFMA rows 0-7 (queries t0..t0+7) and head w+4 in rows 8-15.
// br=0: SEL branch (adds g0*o_s). br=1: WIN branch (adds g1*o_w).
__global__ __launch_bounds__(256, 3) void main_attn_branch(
    const float* __restrict__ q, const float* __restrict__ kg,
    const float* __restrict__ vg,
    const unsigned int* __restrict__ blk_mask,
    const float* __restrict__ Wg, const float* __restrict__ bg,
    float* out)
{
    const int t0   = (S_LEN/TQ - 1 - blockIdx.x) * TQ;   // big tiles first
    const int kv   = blockIdx.y;
    const int br   = blockIdx.z;       // 0 = sel, 1 = win
    const int tid  = threadIdx.x;
    const int w    = tid >> 6;
    const int lane = tid & 63;
    const int quad = lane >> 4;
    const int l4   = lane & 15;

    __shared__ __align__(16) f16 Klds[64*136];   // 17408 B
    __shared__ __align__(16) f16 VP[64*136];     // 17408 B: Vrow, then P (aliased)
    __shared__ __align__(16) f16 Vt[128*72];     // 18432 B   (53248 total)
    f16* __restrict__ Pw = VP + w*1152;          // per-wave P [16][72]

    const int nkb = ((t0 + TQ - 1) >> 6) + 1;
    const int wlo_tile = t0 - WIN + 1;

    // active key-block mask for this branch (block-uniform)
    unsigned act = 0;
    if (br == 0) {
        unsigned um = 0;
        for (int i = 0; i < TQ; ++i) um |= blk_mask[kv*S_LEN + t0 + i];
        act = um & ((1u << nkb) - 1u);
    } else {
        for (int kb2 = 0; kb2 < nkb; ++kb2)
            if (kb2*64 + 63 >= wlo_tile) act |= (1u << kb2);
    }
    if (act == 0) return;   // uniform; no barrier crossed yet

    // Q A-frags: row l4 -> query t0+(l4&7), head w + 4*(l4>>3)
    f16x8 aq[4];
    {
        const float* qrow = q + ((size_t)((t0 + (l4 & 7))*HQ + kv*8 + w + (l4 >> 3)*4))*DH;
        #pragma unroll
        for (int ks = 0; ks < 4; ++ks) {
            float4 A = *(const float4*)(qrow + ks*32 + quad*8);
            float4 B = *(const float4*)(qrow + ks*32 + quad*8 + 4);
            aq[ks] = cvt8s(A, B, SCALE);
        }
    }

    int srow[4]; int headc[4]; unsigned selm[4];
    #pragma unroll
    for (int r = 0; r < 4; ++r) {
        int row = quad*4 + r;
        srow[r]  = t0 + (row & 7);
        headc[r] = kv*8 + w + (row >> 3)*4;
        selm[r]  = blk_mask[kv*S_LEN + srow[r]];
    }

    f32x4 o[8];
    #pragma unroll
    for (int nf = 0; nf < 8; ++nf) o[nf] = (f32x4){0.f,0.f,0.f,0.f};
    float m_[4], l_[4];
    #pragma unroll
    for (int r = 0; r < 4; ++r) { m_[r] = -1e30f; l_[r] = 0.f; }

    int key_[4], cg_[4];
    #pragma unroll
    for (int i = 0; i < 4; ++i) { int idx = i*256 + tid; key_[i] = idx >> 4; cg_[i] = idx & 15; }

    float4 pkA[4], pkB[4], pvA[4], pvB[4];
    int kb = __builtin_ctz(act); act &= act - 1;
    #pragma unroll
    for (int i = 0; i < 4; ++i) {
        const float* sK = kg + ((size_t)(kb*64 + key_[i])*HKV + kv)*DH + cg_[i]*8;
        const float* sV = vg + ((size_t)(kb*64 + key_[i])*HKV + kv)*DH + cg_[i]*8;
        pkA[i] = *(const float4*)sK; pkB[i] = *(const float4*)(sK + 4);
        pvA[i] = *(const float4*)sV; pvB[i] = *(const float4*)(sV + 4);
    }

    while (true) {
        __syncthreads();   // prior compute done with Klds/Vt/P
        #pragma unroll
        for (int i = 0; i < 4; ++i) {
            *(f16x8*)&Klds[key_[i]*136 + cg_[i]*8] = cvt8(pkA[i], pkB[i]);
            *(f16x8*)&VP[key_[i]*136 + cg_[i]*8]   = cvt8(pvA[i], pvB[i]);
        }
        __syncthreads();

        const int cur = kb;
        const bool more = (act != 0);
        if (more) {
            kb = __builtin_ctz(act); act &= act - 1;
            #pragma unroll
            for (int i = 0; i < 4; ++i) {
                const float* sK = kg + ((size_t)(kb*64 + key_[i])*HKV + kv)*DH + cg_[i]*8;
                const float* sV = vg + ((size_t)(kb*64 + key_[i])*HKV + kv)*DH + cg_[i]*8;
                pkA[i] = *(const float4*)sK; pkB[i] = *(const float4*)(sK + 4);
                pvA[i] = *(const float4*)sV; pvB[i] = *(const float4*)(sV + 4);
            }
        }

        // transpose VP(Vrow)[key][d] -> Vt[d][key]
        #pragma unroll
        for (int i = 0; i < 4; ++i) {
            int idx = i*256 + tid;
            int d = idx & 127, kg8 = idx >> 7;
            f16x8 h;
            #pragma unroll
            for (int j = 0; j < 8; ++j) h[j] = VP[(kg8*8 + j)*136 + d];
            *(f16x8*)&Vt[d*72 + kg8*8] = h;
        }
        __syncthreads();   // Vrow dead; VP region now usable as P

        // S = Q K^T (pre-scaled)
        f32x4 sc[4];
        #pragma unroll
        for (int nt = 0; nt < 4; ++nt) {
            sc[nt] = (f32x4){0.f,0.f,0.f,0.f};
            #pragma unroll
            for (int ks = 0; ks < 4; ++ks) {
                f16x8 bk = *(const f16x8*)&Klds[(nt*16 + l4)*136 + ks*32 + quad*8];
                sc[nt] = __builtin_amdgcn_mfma_f32_16x16x32_f16(aq[ks], bk, sc[nt], 0, 0, 0);
            }
        }

        const int keyb = cur*64;
        // ---- single-branch online softmax
        float rmax[4] = {-1e30f,-1e30f,-1e30f,-1e30f};
        #pragma unroll
        for (int nt = 0; nt < 4; ++nt) {
            int key = keyb + nt*16 + l4;
            #pragma unroll
            for (int r = 0; r < 4; ++r) {
                bool ok = (key <= srow[r]) &&
                          (br ? (key > srow[r] - WIN) : (bool)((selm[r] >> cur) & 1u));
                rmax[r] = fmaxf(rmax[r], ok ? sc[nt][r] : -1e30f);
            }
        }
        float alpha[4];
        #pragma unroll
        for (int r = 0; r < 4; ++r) {
            #pragma unroll
            for (int off = 1; off < 16; off <<= 1)
                rmax[r] = fmaxf(rmax[r], __shfl_xor(rmax[r], off));
            float nm = fmaxf(m_[r], rmax[r]);
            alpha[r] = __expf(m_[r] - nm);
            m_[r] = nm;
        }
        float rs[4] = {0.f,0.f,0.f,0.f};
        #pragma unroll
        for (int nt = 0; nt < 4; ++nt) {
            int key = keyb + nt*16 + l4;
            #pragma unroll
            for (int r = 0; r < 4; ++r) {
                bool ok = (key <= srow[r]) &&
                          (br ? (key > srow[r] - WIN) : (bool)((selm[r] >> cur) & 1u));
                float p = ok ? __expf(sc[nt][r] - m_[r]) : 0.f;
                rs[r] += p;
                Pw[(quad*4 + r)*72 + nt*16 + l4] = (f16)p;
            }
        }
        #pragma unroll
        for (int r = 0; r < 4; ++r) {
            #pragma unroll
            for (int off = 1; off < 16; off <<= 1) rs[r] += __shfl_xor(rs[r], off);
            l_[r] = l_[r]*alpha[r] + rs[r];
        }
        #pragma unroll
        for (int nf = 0; nf < 8; ++nf) {
            #pragma unroll
            for (int r = 0; r < 4; ++r) o[nf][r] *= alpha[r];
        }
        #pragma unroll
        for (int ks2 = 0; ks2 < 2; ++ks2) {
            f16x8 ap = *(const f16x8*)&Pw[l4*72 + ks2*32 + quad*8];
            #pragma unroll
            for (int nf = 0; nf < 8; ++nf) {
                f16x8 bv = *(const f16x8*)&Vt[(nf*16 + l4)*72 + ks2*32 + quad*8];
                o[nf] = __builtin_amdgcn_mfma_f32_16x16x32_f16(ap, bv, o[nf], 0, 0, 0);
            }
        }

        if (!more) break;
    }

    // epilogue: gate (g0 for sel, g1 for win) + atomicAdd into out
    const int gidx = br;   // Wg column
    #pragma unroll
    for (int r = 0; r < 4; ++r) {
        const float inv = 1.f / fmaxf(l_[r], 1e-9f);
        float gp = 0.f;
        const float* qrow = q + ((size_t)(srow[r]*HQ + headc[r]))*DH + l4*8;
        #pragma unroll
        for (int j = 0; j < 8; ++j)
            gp += qrow[j] * Wg[(l4*8 + j)*3 + gidx];
        #pragma unroll
        for (int off = 1; off < 16; off <<= 1) gp += __shfl_xor(gp, off);
        float gate = 1.f/(1.f + __expf(-(gp + bg[gidx])));
        const float gi = gate * inv;
        #pragma unroll
        for (int nf = 0; nf < 8; ++nf) {
            size_t oi = ((size_t)(srow[r]*HQ + headc[r]))*DH + nf*16 + l4;
            atomicAdd(&out[oi], gi * o[nf][r]);
        }
    }
}

// ---------------------------------------------------------------- launcher
extern "C" void kernel_launch(void* const* d_in, const int* in_sizes, int n_in,
                              void* d_out, int out_size, void* d_ws, size_t ws_size,
                              hipStream_t stream) {
    const float* q   = (const float*)d_in[0];
    const float* k   = (const float*)d_in[1];
    const float* v   = (const float*)d_in[2];
    const float* Wk  = (const float*)d_in[3];
    const float* bk  = (const float*)d_in[4];
    const float* Wv  = (const float*)d_in[5];
    const float* bv  = (const float*)d_in[6];
    const float* pek = (const float*)d_in[7];
    const float* pev = (const float*)d_in[8];
    const float* Wg  = (const float*)d_in[9];
    const float* bg  = (const float*)d_in[10];
    float* out = (float*)d_out;

    char* ws = (char*)d_ws;
    float* ck = (float*)ws;                                //  97,280 B
    float* cv = (float*)(ws + 98304);                      //  97,280 B
    unsigned int* blk_mask = (unsigned int*)(ws + 196608); //  12,288 B

    compress_init_kernel<<<dim3(190), 256, 0, stream>>>(bk, bv, ck, cv);
    compress_partial_kernel<<<dim3(19, 4, 8), 256, 0, stream>>>(
        k, v, Wk, Wv, pek, pev, ck, cv);
    // writes g2-gated cmp_o into out (covers every element) + blk_mask
    cmp_attn_kernel<<<dim3(S_LEN/4, HKV), 256, 0, stream>>>(
        q, ck, cv, Wg, bg, out, blk_mask);
    // sel/win items atomicAdd their gated terms on top
    main_attn_branch<<<dim3(S_LEN/TQ, HKV, 2), 256, 0, stream>>>(
        q, k, v, blk_mask, Wg, bg, out);
}

// Round 9
// 234.694 us; speedup vs baseline: 1.6533x; 1.6533x over previous
//
#include <hip/hip_runtime.h>

// NSA attention.
// K0: init ck/cv with bias. K1: K-split compress (fp32, atomics).
// K2: cmp attention + topk via f16 hi/lo MFMA (fp32-grade logits), per-wave topk.
// K3: R7 main attention: query-tiled MFMA flash, register prefetch, in-loop V
//     transpose, reads cmp_o in place from out.

#define S_LEN 1536
#define HQ    16
#define HKV   2
#define DH    128
#define TC    95
#define WIN   512
#define TQ    16
#define SCALE 0.08838834764831845f   // 1/sqrt(128)

typedef _Float16 f16;
typedef f16   f16x4 __attribute__((ext_vector_type(4)));
typedef f16   f16x8 __attribute__((ext_vector_type(8)));
typedef float f32x4 __attribute__((ext_vector_type(4)));

__device__ inline f16x8 cvt8(float4 A, float4 B) {
    f16x8 h;
    h[0]=(f16)A.x; h[1]=(f16)A.y; h[2]=(f16)A.z; h[3]=(f16)A.w;
    h[4]=(f16)B.x; h[5]=(f16)B.y; h[6]=(f16)B.z; h[7]=(f16)B.w;
    return h;
}
__device__ inline f16x8 cvt8s(float4 A, float4 B, float s) {
    f16x8 h;
    h[0]=(f16)(A.x*s); h[1]=(f16)(A.y*s); h[2]=(f16)(A.z*s); h[3]=(f16)(A.w*s);
    h[4]=(f16)(B.x*s); h[5]=(f16)(B.y*s); h[6]=(f16)(B.z*s); h[7]=(f16)(B.w*s);
    return h;
}

// ---------------------------------------------------------------- kernel 0
__global__ __launch_bounds__(256) void compress_init_kernel(
    const float* __restrict__ bk, const float* __restrict__ bv,
    float* __restrict__ ck, float* __restrict__ cv)
{
    int i = blockIdx.x * 256 + threadIdx.x;       // 190 blocks * 256 = 48640
    int which = i >= TC*HKV*DH;
    int j = i - which*(TC*HKV*DH);
    int d = j & 127;
    (which ? cv : ck)[j] = (which ? bv : bk)[d];
}

// ---------------------------------------------------------------- kernel 1
__global__ __launch_bounds__(256) void compress_partial_kernel(
    const float* __restrict__ kin, const float* __restrict__ vin,
    const float* __restrict__ Wk,  const float* __restrict__ Wv,
    const float* __restrict__ pek, const float* __restrict__ pev,
    float* __restrict__ ck, float* __restrict__ cv)
{
    const int t0    = blockIdx.x * 5;
    const int kv    = blockIdx.y >> 1;
    const int which = blockIdx.y & 1;
    const int kc    = blockIdx.z;
    const float* __restrict__ x  = which ? vin : kin;
    const float* __restrict__ W  = which ? Wv  : Wk;
    const float* __restrict__ pe = which ? pev : pek;
    float* __restrict__ outp     = which ? cv  : ck;
    const int tid = threadIdx.x;
    const int hh  = tid >> 7;
    const int d   = tid & 127;

    __shared__ float xs[2][5][128];
    __shared__ float racc[5][128];
    float acc[5] = {0.f, 0.f, 0.f, 0.f, 0.f};

    #pragma unroll
    for (int il = 0; il < 2; ++il) {
        const int l = kc*4 + hh*2 + il;
        float p = pe[l*DH + d];
        #pragma unroll
        for (int tt = 0; tt < 5; ++tt) {
            int row = (t0 + tt)*16 + l;
            xs[hh][tt][d] = x[(row*HKV + kv)*DH + d] + p;
        }
        __syncthreads();
        const float* wcol = W + l*DH*DH + d;
        #pragma unroll 8
        for (int dd = 0; dd < 128; ++dd) {
            float wv = wcol[dd*DH];
            #pragma unroll
            for (int tt = 0; tt < 5; ++tt) acc[tt] += xs[hh][tt][dd] * wv;
        }
        __syncthreads();
    }
    if (hh == 1) {
        #pragma unroll
        for (int tt = 0; tt < 5; ++tt) racc[tt][d] = acc[tt];
    }
    __syncthreads();
    if (hh == 0) {
        #pragma unroll
        for (int tt = 0; tt < 5; ++tt)
            atomicAdd(&outp[((t0 + tt)*HKV + kv)*DH + d], acc[tt] + racc[tt][d]);
    }
}

// ---------------------------------------------------------------- kernel 2
// MFMA cmp attention. Block = (8 queries, kv); 64 rows = q*8+h; wave w owns
// rows [w*16, w*16+16) = queries {2w, 2w+1}. Logits via f16 hi/lo 3-term MFMA
// (error ~2^-22 — selection-exact vs fp32 ref). PV via f16-prob MFMA.
__global__ __launch_bounds__(256) void cmp_attn_mfma(
    const float* __restrict__ q, const float* __restrict__ ck,
    const float* __restrict__ cv, float* __restrict__ cmp_o,
    unsigned int* __restrict__ blk_mask)
{
    const int s0   = blockIdx.x * 8;
    const int kv   = blockIdx.y;
    const int tid  = threadIdx.x;
    const int w    = tid >> 6;
    const int lane = tid & 63;
    const int quad = lane >> 4;
    const int l4   = lane & 15;

    __shared__ __align__(16) char BUF[52736];
    f16* __restrict__ CKH = (f16*)BUF;             // [96][136] hi
    f16* __restrict__ CKL = (f16*)(BUF + 26112);   // [96][136] lo
    // phase-2 reuse:
    f16* __restrict__ CVR = (f16*)BUF;             // [96][136]
    f16* __restrict__ CVT = (f16*)(BUF + 26112);   // [128][104]
    // phase-3 reuse of [0, 26112):
    f16*   __restrict__ Pw = (f16*)BUF + w*1664;   // per-wave P [16][104]
    float* __restrict__ SC = (float*)(BUF + 13312);// [8][96] score
    float* __restrict__ PO = (float*)(BUF + 16384);// [8][24] pooled

    // ---- stage ck hi/lo (row 95 zeroed)
    #pragma unroll
    for (int i = 0; i < 6; ++i) {
        int idx = i*256 + tid;                     // 96 rows x 16 chunks
        int row = idx >> 4, cg = idx & 15;
        float4 A = make_float4(0.f,0.f,0.f,0.f), B = A;
        if (row < TC) {
            const float* src = ck + ((size_t)(row*HKV + kv))*DH + cg*8;
            A = *(const float4*)src; B = *(const float4*)(src + 4);
        }
        f16x8 h = cvt8(A, B);
        f16x8 l;
        l[0]=(f16)(A.x-(float)h[0]); l[1]=(f16)(A.y-(float)h[1]);
        l[2]=(f16)(A.z-(float)h[2]); l[3]=(f16)(A.w-(float)h[3]);
        l[4]=(f16)(B.x-(float)h[4]); l[5]=(f16)(B.y-(float)h[5]);
        l[6]=(f16)(B.z-(float)h[6]); l[7]=(f16)(B.w-(float)h[7]);
        *(f16x8*)&CKH[row*136 + cg*8] = h;
        *(f16x8*)&CKL[row*136 + cg*8] = l;
    }

    // ---- q A-frags hi/lo (SCALE folded before split)
    const int qrow_local = w*16 + l4;              // row = q*8 + h
    const int sA = s0 + (qrow_local >> 3);
    const int hA = qrow_local & 7;
    f16x8 aqh[4], aql[4];
    {
        const float* qrow = q + ((size_t)(sA*HQ + kv*8 + hA))*DH;
        #pragma unroll
        for (int ks = 0; ks < 4; ++ks) {
            float4 A = *(const float4*)(qrow + ks*32 + quad*8);
            float4 B = *(const float4*)(qrow + ks*32 + quad*8 + 4);
            A.x*=SCALE; A.y*=SCALE; A.z*=SCALE; A.w*=SCALE;
            B.x*=SCALE; B.y*=SCALE; B.z*=SCALE; B.w*=SCALE;
            f16x8 h = cvt8(A, B);
            f16x8 l;
            l[0]=(f16)(A.x-(float)h[0]); l[1]=(f16)(A.y-(float)h[1]);
            l[2]=(f16)(A.z-(float)h[2]); l[3]=(f16)(A.w-(float)h[3]);
            l[4]=(f16)(B.x-(float)h[4]); l[5]=(f16)(B.y-(float)h[5]);
            l[6]=(f16)(B.z-(float)h[6]); l[7]=(f16)(B.w-(float)h[7]);
            aqh[ks] = h; aql[ks] = l;
        }
    }
    __syncthreads();

    // ---- logits: 6 col-tiles x 4 K-steps x 3 terms
    f32x4 sc[6];
    #pragma unroll
    for (int nt = 0; nt < 6; ++nt) {
        sc[nt] = (f32x4){0.f,0.f,0.f,0.f};
        #pragma unroll
        for (int ks = 0; ks < 4; ++ks) {
            f16x8 bh = *(const f16x8*)&CKH[(nt*16 + l4)*136 + ks*32 + quad*8];
            f16x8 bl = *(const f16x8*)&CKL[(nt*16 + l4)*136 + ks*32 + quad*8];
            sc[nt] = __builtin_amdgcn_mfma_f32_16x16x32_f16(aqh[ks], bh, sc[nt], 0, 0, 0);
            sc[nt] = __builtin_amdgcn_mfma_f32_16x16x32_f16(aql[ks], bh, sc[nt], 0, 0, 0);
            sc[nt] = __builtin_amdgcn_mfma_f32_16x16x32_f16(aqh[ks], bl, sc[nt], 0, 0, 0);
        }
    }
    __syncthreads();   // CK region free

    // ---- stage cv rows f16 (row 95 zeroed)
    #pragma unroll
    for (int i = 0; i < 6; ++i) {
        int idx = i*256 + tid;
        int row = idx >> 4, cg = idx & 15;
        float4 A = make_float4(0.f,0.f,0.f,0.f), B = A;
        if (row < TC) {
            const float* src = cv + ((size_t)(row*HKV + kv))*DH + cg*8;
            A = *(const float4*)src; B = *(const float4*)(src + 4);
        }
        *(f16x8*)&CVR[row*136 + cg*8] = cvt8(A, B);
    }
    __syncthreads();
    // ---- transpose CVR[t][d] -> CVT[d][t]
    #pragma unroll
    for (int i = 0; i < 6; ++i) {
        int idx = i*256 + tid;                     // 128 d x 12 t-chunks
        int d = idx & 127, tc = idx >> 7;
        f16x8 h;
        #pragma unroll
        for (int j = 0; j < 8; ++j) h[j] = CVR[(tc*8 + j)*136 + d];
        *(f16x8*)&CVT[d*104 + tc*8] = h;
    }
    __syncthreads();   // CVR dead; [0,26112) now P/SC/PO

    // ---- softmax (regs). Rows quad*4+r all share query s_q (quad>>1).
    const int s_q = s0 + 2*w + (quad >> 1);
    const int nv  = (s_q >= 31) ? (((s_q - 31) >> 4) + 1) : 0;
    bool valid[6];
    #pragma unroll
    for (int nt = 0; nt < 6; ++nt) valid[nt] = (nt*16 + l4) < nv;

    float pn[6][4];
    float lsum[4];
    #pragma unroll
    for (int r = 0; r < 4; ++r) {
        float m = -3.4e38f;
        #pragma unroll
        for (int nt = 0; nt < 6; ++nt) m = fmaxf(m, valid[nt] ? sc[nt][r] : -3.4e38f);
        #pragma unroll
        for (int off = 1; off < 16; off <<= 1) m = fmaxf(m, __shfl_xor(m, off));
        float s = 0.f;
        #pragma unroll
        for (int nt = 0; nt < 6; ++nt) {
            float e = valid[nt] ? __expf(sc[nt][r] - m) : 0.f;
            pn[nt][r] = e;
            s += e;
        }
        #pragma unroll
        for (int off = 1; off < 16; off <<= 1) s += __shfl_xor(s, off);
        const float inv = 1.f / fmaxf(s, 1e-9f);
        #pragma unroll
        for (int nt = 0; nt < 6; ++nt) pn[nt][r] *= inv;
        lsum[r] = s;   // unused, kept for clarity
    }
    (void)lsum;

    // ---- write P (f16) + score (fp32)
    #pragma unroll
    for (int nt = 0; nt < 6; ++nt) {
        #pragma unroll
        for (int r = 0; r < 4; ++r)
            Pw[(quad*4 + r)*104 + nt*16 + l4] = (f16)pn[nt][r];
        float scq = pn[nt][0] + pn[nt][1] + pn[nt][2] + pn[nt][3];
        scq += __shfl_xor(scq, 16);    // partner quad: full 8-head sum
        if ((quad & 1) == 0)
            SC[(w*2 + (quad >> 1))*96 + nt*16 + l4] = scq;
    }

    // ---- pooled + stable top-16 (wave-local; lanes 0-23 -> q0, 32-55 -> q1)
    {
        int qi = lane >> 5;
        int o  = lane & 31;
        bool sel = false;
        if (o < 24) {
            float acc = 0.f, cnt = 0.f;
            #pragma unroll
            for (int j = 0; j < 5; ++j) {
                int wd = o*4 + j;
                if (wd < TC) { acc += SC[(w*2 + qi)*96 + wd]; cnt += 1.f; }
            }
            PO[(w*2 + qi)*24 + o] = acc / cnt;
        }
        // wave-local LDS ordering: same wave wrote PO above
        if (o < 24) {
            float pvv = PO[(w*2 + qi)*24 + o];
            int rank = 0;
            #pragma unroll
            for (int j = 0; j < 24; ++j) {
                float pj = PO[(w*2 + qi)*24 + j];
                rank += ((pj > pvv) || (pj == pvv && j < o)) ? 1 : 0;
            }
            sel = rank < 16;
        }
        unsigned long long b = __ballot(sel);
        if (lane == 0) {
            blk_mask[kv*S_LEN + s0 + 2*w]     = (unsigned int)(b & 0xFFFFFFull);
            blk_mask[kv*S_LEN + s0 + 2*w + 1] = (unsigned int)((b >> 32) & 0xFFFFFFull);
        }
    }

    // ---- PV: O[rows 16][d 128] = P[16][96] x CVT[128][96]^T
    f32x4 O[8];
    #pragma unroll
    for (int nf = 0; nf < 8; ++nf) O[nf] = (f32x4){0.f,0.f,0.f,0.f};
    #pragma unroll
    for (int ks2 = 0; ks2 < 3; ++ks2) {
        f16x8 ap = *(const f16x8*)&Pw[l4*104 + ks2*32 + quad*8];
        #pragma unroll
        for (int nf = 0; nf < 8; ++nf) {
            f16x8 bv = *(const f16x8*)&CVT[(nf*16 + l4)*104 + ks2*32 + quad*8];
            O[nf] = __builtin_amdgcn_mfma_f32_16x16x32_f16(ap, bv, O[nf], 0, 0, 0);
        }
    }
    // ---- write cmp_o (plain; main kernel applies the g2 gate)
    #pragma unroll
    for (int r = 0; r < 4; ++r) {
        const int h_r = (quad & 1)*4 + r;
        const size_t base = ((size_t)(s_q*HQ + kv*8 + h_r))*DH;
        #pragma unroll
        for (int nf = 0; nf < 8; ++nf)
            cmp_o[base + nf*16 + l4] = O[nf][r];
    }
}

// ---------------------------------------------------------------- kernel 3
// R7 main attention (verbatim): 256 thr = 4 waves = 4 heads, z head-half,
// fp32 k/v reads, in-loop V transpose, register prefetch of next key-block.
__global__ __launch_bounds__(256, 2) void main_attn_mfma(
    const float* __restrict__ q, const float* __restrict__ kg,
    const float* __restrict__ vg, const float* cmp_o,   // aliases out!
    const unsigned int* __restrict__ blk_mask,
    const float* __restrict__ Wg, const float* __restrict__ bg,
    float* out)
{
    const int t0   = (S_LEN/TQ - 1 - blockIdx.x) * TQ;   // big tiles first
    const int kv   = blockIdx.y;
    const int z    = blockIdx.z;
    const int tid  = threadIdx.x;
    const int w    = tid >> 6;
    const int lane = tid & 63;
    const int quad = lane >> 4;
    const int l4   = lane & 15;
    const int head = z*4 + w;

    __shared__ __align__(16) f16 Klds[64*136];
    __shared__ __align__(16) f16 Vrow[64*136];
    __shared__ __align__(16) f16 Vt[128*72];
    __shared__ __align__(16) f16 Plds[4][16*72];
    f16* __restrict__ Pw = Plds[w];

    f16x8 aq[4];
    {
        const float* qrow = q + ((size_t)(t0 + l4)*HQ + kv*8 + head)*DH;
        #pragma unroll
        for (int ks = 0; ks < 4; ++ks) {
            float4 A = *(const float4*)(qrow + ks*32 + quad*8);
            float4 B = *(const float4*)(qrow + ks*32 + quad*8 + 4);
            aq[ks] = cvt8s(A, B, SCALE);
        }
    }

    int srow[4]; unsigned selm[4];
    #pragma unroll
    for (int r = 0; r < 4; ++r) {
        srow[r] = t0 + quad*4 + r;
        selm[r] = blk_mask[kv*S_LEN + srow[r]];
    }
    unsigned um = 0;
    for (int i = 0; i < TQ; ++i) um |= blk_mask[kv*S_LEN + t0 + i];

    f32x4 o_s[8], o_w[8];
    #pragma unroll
    for (int nf = 0; nf < 8; ++nf) {
        o_s[nf] = (f32x4){0.f,0.f,0.f,0.f};
        o_w[nf] = (f32x4){0.f,0.f,0.f,0.f};
    }
    float m_s[4], l_s[4], m_w[4], l_w[4];
    #pragma unroll
    for (int r = 0; r < 4; ++r) { m_s[r]=-1e30f; l_s[r]=0.f; m_w[r]=-1e30f; l_w[r]=0.f; }

    const int nkb = ((t0 + TQ - 1) >> 6) + 1;
    const int wlo_tile = t0 - WIN + 1;

    unsigned act = 0;
    for (int kb2 = 0; kb2 < nkb; ++kb2) {
        bool a = ((um >> kb2) & 1u) || ((kb2*64 + 63) >= wlo_tile);
        if (a) act |= (1u << kb2);
    }

    int key_[4], cg_[4];
    #pragma unroll
    for (int i = 0; i < 4; ++i) { int idx = i*256 + tid; key_[i] = idx >> 4; cg_[i] = idx & 15; }

    float4 pkA[4], pkB[4], pvA[4], pvB[4];
    int kb = __builtin_ctz(act); act &= act - 1;
    #pragma unroll
    for (int i = 0; i < 4; ++i) {
        const float* sK = kg + ((size_t)(kb*64 + key_[i])*HKV + kv)*DH + cg_[i]*8;
        const float* sV = vg + ((size_t)(kb*64 + key_[i])*HKV + kv)*DH + cg_[i]*8;
        pkA[i] = *(const float4*)sK; pkB[i] = *(const float4*)(sK + 4);
        pvA[i] = *(const float4*)sV; pvB[i] = *(const float4*)(sV + 4);
    }

    while (true) {
        __syncthreads();
        #pragma unroll
        for (int i = 0; i < 4; ++i) {
            *(f16x8*)&Klds[key_[i]*136 + cg_[i]*8] = cvt8(pkA[i], pkB[i]);
            *(f16x8*)&Vrow[key_[i]*136 + cg_[i]*8] = cvt8(pvA[i], pvB[i]);
        }
        __syncthreads();

        const int cur = kb;
        const bool more = (act != 0);
        if (more) {
            kb = __builtin_ctz(act); act &= act - 1;
            #pragma unroll
            for (int i = 0; i < 4; ++i) {
                const float* sK = kg + ((size_t)(kb*64 + key_[i])*HKV + kv)*DH + cg_[i]*8;
                const float* sV = vg + ((size_t)(kb*64 + key_[i])*HKV + kv)*DH + cg_[i]*8;
                pkA[i] = *(const float4*)sK; pkB[i] = *(const float4*)(sK + 4);
                pvA[i] = *(const float4*)sV; pvB[i] = *(const float4*)(sV + 4);
            }
        }

        #pragma unroll
        for (int i = 0; i < 4; ++i) {
            int idx = i*256 + tid;
            int d = idx & 127, kg8 = idx >> 7;
            f16x8 h;
            #pragma unroll
            for (int j = 0; j < 8; ++j) h[j] = Vrow[(kg8*8 + j)*136 + d];
            *(f16x8*)&Vt[d*72 + kg8*8] = h;
        }
        __syncthreads();

        f32x4 sc[4];
        #pragma unroll
        for (int nt = 0; nt < 4; ++nt) {
            sc[nt] = (f32x4){0.f,0.f,0.f,0.f};
            #pragma unroll
            for (int ks = 0; ks < 4; ++ks) {
                f16x8 bk = *(const f16x8*)&Klds[(nt*16 + l4)*136 + ks*32 + quad*8];
                sc[nt] = __builtin_amdgcn_mfma_f32_16x16x32_f16(aq[ks], bk, sc[nt], 0, 0, 0);
            }
        }

        const int keyb = cur*64;
        const bool any_sel = (um >> cur) & 1u;
        const bool any_win = (keyb + 63) >= wlo_tile;
        if (any_sel) {
            float rmax[4] = {-1e30f,-1e30f,-1e30f,-1e30f};
            #pragma unroll
            for (int nt = 0; nt < 4; ++nt) {
                int key = keyb + nt*16 + l4;
                #pragma unroll
                for (int r = 0; r < 4; ++r) {
                    bool ok = (key <= srow[r]) && ((selm[r] >> cur) & 1u);
                    rmax[r] = fmaxf(rmax[r], ok ? sc[nt][r] : -1e30f);
                }
            }
            float alpha[4];
            #pragma unroll
            for (int r = 0; r < 4; ++r) {
                #pragma unroll
                for (int off = 1; off < 16; off <<= 1)
                    rmax[r] = fmaxf(rmax[r], __shfl_xor(rmax[r], off));
                float nm = fmaxf(m_s[r], rmax[r]);
                alpha[r] = __expf(m_s[r] - nm);
                m_s[r] = nm;
            }
            float rs[4] = {0.f,0.f,0.f,0.f};
            #pragma unroll
            for (int nt = 0; nt < 4; ++nt) {
                int key = keyb + nt*16 + l4;
                #pragma unroll
                for (int r = 0; r < 4; ++r) {
                    bool ok = (key <= srow[r]) && ((selm[r] >> cur) & 1u);
                    float p = ok ? __expf(sc[nt][r] - m_s[r]) : 0.f;
                    rs[r] += p;
                    Pw[(quad*4 + r)*72 + nt*16 + l4] = (f16)p;
                }
            }
            #pragma unroll
            for (int r = 0; r < 4; ++r) {
                #pragma unroll
                for (int off = 1; off < 16; off <<= 1) rs[r] += __shfl_xor(rs[r], off);
                l_s[r] = l_s[r]*alpha[r] + rs[r];
            }
            #pragma unroll
            for (int nf = 0; nf < 8; ++nf) {
                #pragma unroll
                for (int r = 0; r < 4; ++r) o_s[nf][r] *= alpha[r];
            }
            #pragma unroll
            for (int ks2 = 0; ks2 < 2; ++ks2) {
                f16x8 ap = *(const f16x8*)&Pw[l4*72 + ks2*32 + quad*8];
                #pragma unroll
                for (int nf = 0; nf < 8; ++nf) {
                    f16x8 bv = *(const f16x8*)&Vt[(nf*16 + l4)*72 + ks2*32 + quad*8];
                    o_s[nf] = __builtin_amdgcn_mfma_f32_16x16x32_f16(ap, bv, o_s[nf], 0, 0, 0);
                }
            }
        }
        if (any_win) {
            float rmax[4] = {-1e30f,-1e30f,-1e30f,-1e30f};
            #pragma unroll
            for (int nt = 0; nt < 4; ++nt) {
                int key = keyb + nt*16 + l4;
                #pragma unroll
                for (int r = 0; r < 4; ++r) {
                    bool ok = (key <= srow[r]) && (key > srow[r] - WIN);
                    rmax[r] = fmaxf(rmax[r], ok ? sc[nt][r] : -1e30f);
                }
            }
            float alpha[4];
            #pragma unroll
            for (int r = 0; r < 4; ++r) {
                #pragma unroll
                for (int off = 1; off < 16; off <<= 1)
                    rmax[r] = fmaxf(rmax[r], __shfl_xor(rmax[r], off));
                float nm = fmaxf(m_w[r], rmax[r]);
                alpha[r] = __expf(m_w[r] - nm);
                m_w[r] = nm;
            }
            float rs[4] = {0.f,0.f,0.f,0.f};
            #pragma unroll
            for (int nt = 0; nt < 4; ++nt) {
                int key = keyb + nt*16 + l4;
                #pragma unroll
                for (int r = 0; r < 4; ++r) {
                    bool ok = (key <= srow[r]) && (key > srow[r] - WIN);
                    float p = ok ? __expf(sc[nt][r] - m_w[r]) : 0.f;
                    rs[r] += p;
                    Pw[(quad*4 + r)*72 + nt*16 + l4] = (f16)p;
                }
            }
            #pragma unroll
            for (int r = 0; r < 4; ++r) {
                #pragma unroll
                for (int off = 1; off < 16; off <<= 1) rs[r] += __shfl_xor(rs[r], off);
                l_w[r] = l_w[r]*alpha[r] + rs[r];
            }
            #pragma unroll
            for (int nf = 0; nf < 8; ++nf) {
                #pragma unroll
                for (int r = 0; r < 4; ++r) o_w[nf][r] *= alpha[r];
            }
            #pragma unroll
            for (int ks2 = 0; ks2 < 2; ++ks2) {
                f16x8 ap = *(const f16x8*)&Pw[l4*72 + ks2*32 + quad*8];
                #pragma unroll
                for (int nf = 0; nf < 8; ++nf) {
                    f16x8 bv = *(const f16x8*)&Vt[(nf*16 + l4)*72 + ks2*32 + quad*8];
                    o_w[nf] = __builtin_amdgcn_mfma_f32_16x16x32_f16(ap, bv, o_w[nf], 0, 0, 0);
                }
            }
        }

        if (!more) break;
    }

    float inv_s[4], inv_w[4];
    #pragma unroll
    for (int r = 0; r < 4; ++r) {
        inv_s[r] = 1.f / fmaxf(l_s[r], 1e-9f);
        inv_w[r] = 1.f / fmaxf(l_w[r], 1e-9f);
    }
    float gt[4][3];
    #pragma unroll
    for (int r = 0; r < 4; ++r) {
        float p0 = 0.f, p1 = 0.f, p2 = 0.f;
        const float* qrow = q + ((size_t)srow[r]*HQ + kv*8 + head)*DH + l4*8;
        #pragma unroll
        for (int j = 0; j < 8; ++j) {
            float qv = qrow[j];
            int d = l4*8 + j;
            p0 += qv * Wg[d*3 + 0];
            p1 += qv * Wg[d*3 + 1];
            p2 += qv * Wg[d*3 + 2];
        }
        #pragma unroll
        for (int off = 1; off < 16; off <<= 1) {
            p0 += __shfl_xor(p0, off);
            p1 += __shfl_xor(p1, off);
            p2 += __shfl_xor(p2, off);
        }
        gt[r][0] = 1.f/(1.f + __expf(-(p0 + bg[0])));
        gt[r][1] = 1.f/(1.f + __expf(-(p1 + bg[1])));
        gt[r][2] = 1.f/(1.f + __expf(-(p2 + bg[2])));
    }
    #pragma unroll
    for (int nf = 0; nf < 8; ++nf) {
        int d = nf*16 + l4;
        #pragma unroll
        for (int r = 0; r < 4; ++r) {
            size_t oi = ((size_t)srow[r]*HQ + kv*8 + head)*DH + d;
            float cm = cmp_o[oi];
            out[oi] = gt[r][0]*o_s[nf][r]*inv_s[r]
                    + gt[r][1]*o_w[nf][r]*inv_w[r]
                    + gt[r][2]*cm;
        }
    }
}

// ---------------------------------------------------------------- launcher
extern "C" void kernel_launch(void* const* d_in, const int* in_sizes, int n_in,
                              void* d_out, int out_size, void* d_ws, size_t ws_size,
                              hipStream_t stream) {
    const float* q   = (const float*)d_in[0];
    const float* k   = (const float*)d_in[1];
    const float* v   = (const float*)d_in[2];
    const float* Wk  = (const float*)d_in[3];
    const float* bk  = (const float*)d_in[4];
    const float* Wv  = (const float*)d_in[5];
    const float* bv  = (const float*)d_in[6];
    const float* pek = (const float*)d_in[7];
    const float* pev = (const float*)d_in[8];
    const float* Wg  = (const float*)d_in[9];
    const float* bg  = (const float*)d_in[10];
    float* out = (float*)d_out;

    char* ws = (char*)d_ws;
    float* ck = (float*)ws;                                //  97,280 B
    float* cv = (float*)(ws + 98304);                      //  97,280 B
    unsigned int* blk_mask = (unsigned int*)(ws + 196608); //  12,288 B
    float* cmp_o = out;

    compress_init_kernel<<<dim3(190), 256, 0, stream>>>(bk, bv, ck, cv);
    compress_partial_kernel<<<dim3(19, 4, 8), 256, 0, stream>>>(
        k, v, Wk, Wv, pek, pev, ck, cv);
    cmp_attn_mfma<<<dim3(S_LEN/8, HKV), 256, 0, stream>>>(
        q, ck, cv, cmp_o, blk_mask);
    main_attn_mfma<<<dim3(S_LEN/TQ, HKV, 2), 256, 0, stream>>>(
        q, k, v, cmp_o, blk_mask, Wg, bg, out);
}